// Round 9
// baseline (470.670 us; speedup 1.0000x reference)
//
#include <hip/hip_runtime.h>

// LSTMDecoder fused — round 7 rewrite (resubmit r9; infra failures r7/r8, never ran).
// r6 diagnosis: latency-bound on per-wave L2 weight stream (VGPR=128 -> ~2 loads in flight,
// 830 x ~200cy). Fix: (1) async double-buffered LDS weight staging (global_load_lds, 16KB
// phases, weights hit L2 once per BLOCK); (2) 32x32x16 MFMA with 32 batch/wave (halves
// weight traffic per row, identity C/D->B repack).
// Layout: A/B kmap2(g,j) = (j&3) + 8*(j>>2) + 4*g, g = lane>>5. C/D (m74/m101):
// col = lane&31 (batch), row = (reg&3)+8*(reg>>2)+4*(lane>>5)  ==> B slot j = reg (lo) / reg-8 (hi).
// Same kmap for prep-packed A frags -> any true HW k-order cancels (validated on HW r4/r6).

#define L2E 1.4426950408889634f

typedef _Float16 half8 __attribute__((ext_vector_type(8)));
typedef float f32x16 __attribute__((ext_vector_type(16)));

// region bases in HALF8 units (1 frag = 64 half8 = 1 KB)
#define FWX0 0
#define FWX1 8192
#define FWH1 16384
#define FWX2 24576
#define FWH2 32768
#define FHFC 40960
#define FCFC 43008
#define FMID0 45056
#define FMID1 47104
#define FMID2 49152
#define FOUT1 51200
#define FOUT2 53248
#define FOUT3 55296
#define NBLOB_H8 55808
#define NBLOB_F16 446464   // 872 frags * 512 f16

#define MFMA32(A, B, C) __builtin_amdgcn_mfma_f32_32x32x16_f16(A, B, C, 0, 0, 0)
#define ZERO16 f32x16{0,0,0,0,0,0,0,0,0,0,0,0,0,0,0,0}

// ---------------- prep: pack fp32 weights -> fp16 A-fragment blob (32x32x16 layout) ----------
__global__ void lstm_prep(const float* __restrict__ Wx, const float* __restrict__ Wh,
                          const float* __restrict__ hfcW, const float* __restrict__ cfcW,
                          const float* __restrict__ midW, const float* __restrict__ o1W,
                          const float* __restrict__ o2W, const float* __restrict__ o3W,
                          _Float16* __restrict__ blob)
{
    int idx = blockIdx.x * 256 + threadIdx.x;
    if (idx >= NBLOB_F16) return;

    int frag = idx >> 9;           // 512 f16 per frag
    int rem  = idx & 511;
    int lane = rem >> 3;
    int j    = rem & 7;
    int m    = lane & 31;          // output-feature row within 32-tile
    int g    = lane >> 5;
    int kin  = (j & 3) + 8 * (j >> 2) + 4 * g;   // kmap2

    const float* src;
    int style, N = 0, lf;          // 0 = z (512 cols, gate-scaled), 1 = 128 cols, 2 = out (padded)
    if      (frag < 128) { src = Wx;            lf = frag;       style = 0; }
    else if (frag < 256) { src = Wx + 65536;    lf = frag - 128; style = 0; }
    else if (frag < 384) { src = Wh + 65536;    lf = frag - 256; style = 0; }
    else if (frag < 512) { src = Wx + 131072;   lf = frag - 384; style = 0; }
    else if (frag < 640) { src = Wh + 131072;   lf = frag - 512; style = 0; }
    else if (frag < 672) { src = hfcW;          lf = frag - 640; style = 1; }
    else if (frag < 704) { src = cfcW;          lf = frag - 672; style = 1; }
    else if (frag < 736) { src = midW;          lf = frag - 704; style = 1; }
    else if (frag < 768) { src = midW + 16384;  lf = frag - 736; style = 1; }
    else if (frag < 800) { src = midW + 32768;  lf = frag - 768; style = 1; }
    else if (frag < 832) { src = o1W;           lf = frag - 800; style = 2; N = 103; }
    else if (frag < 864) { src = o2W;           lf = frag - 832; style = 2; N = 119; }
    else                 { src = o3W;           lf = frag - 864; style = 2; N = 11;  }

    float v;
    if (style == 0) {
        int mt = lf >> 5, gate = (lf >> 3) & 3, kc = lf & 7;
        int k = kc * 16 + kin;
        int n = gate * 128 + mt * 32 + m;
        float s = (gate == 2) ? (2.0f * L2E) : (-L2E);  // g-gate tanh form; i/f/o sigmoid form
        v = src[k * 512 + n] * s;
    } else if (style == 1) {
        int mt = lf >> 3, kc = lf & 7;
        v = src[(kc * 16 + kin) * 128 + mt * 32 + m];
    } else {
        int mt = lf >> 3, kc = lf & 7;
        int n = mt * 32 + m;
        v = (n < N) ? src[(kc * 16 + kin) * N + n] : 0.0f;
    }
    blob[idx] = (_Float16)v;
}

// ---------------- main fused kernel ----------------

__device__ __forceinline__ float sigz(float z)   // 1 / (1 + 2^z)
{
    return __builtin_amdgcn_rcpf(1.0f + __builtin_amdgcn_exp2f(z));
}

// phase table: 55 phases, each stages <=16 frags (16 KB) from blob
__device__ __forceinline__ void phase_of(int p, int& b, int& n)
{
    n = 16;
    if (p < 8)        b = FWX0 + (p >> 1) * 2048 + (p & 1) * 1024;           // stageA: mt x {if,go}
    else if (p < 10)  b = FMID0 + (p - 8) * 1024;
    else if (p < 12)  b = FOUT1 + (p - 10) * 1024;
    else if (p < 28) { int q = p - 12, mt = q >> 2, sb = q & 3;
                       b = ((sb & 2) ? FWH1 : FWX1) + mt * 2048 + (sb & 1) * 1024; }
    else if (p < 30)  b = FHFC + (p - 28) * 1024;
    else if (p < 32)  b = FCFC + (p - 30) * 1024;
    else if (p < 34)  b = FMID1 + (p - 32) * 1024;
    else if (p < 36)  b = FOUT2 + (p - 34) * 1024;
    else if (p < 52) { int q = p - 36, mt = q >> 2, sb = q & 3;
                       b = ((sb & 2) ? FWH2 : FWX2) + mt * 2048 + (sb & 1) * 1024; }
    else if (p < 54)  b = FMID2 + (p - 52) * 1024;
    else if (p == 54) { b = FOUT3; n = 8; }
    else             { b = 0; n = 0; }
}

// cooperative async stage: 4 waves x up to 4 global_load_lds (1 frag = 1 KB each)
__device__ __forceinline__ void stage_phase(const _Float16* __restrict__ blob, int base_h8, int nfrags,
                                            _Float16* dst, int wv, int lane)
{
    const char* gbase = (const char*)((const half8*)blob + base_h8);
    auto* d = (__attribute__((address_space(3))) char*)dst;
#pragma unroll
    for (int i = 0; i < 4; ++i) {
        int f = i * 4 + wv;
        if (f < nfrags) {
            __builtin_amdgcn_global_load_lds(
                (const __attribute__((address_space(1))) void*)(gbase + (size_t)(f * 64 + lane) * 16),
                (__attribute__((address_space(3))) void*)(d + f * 1024), 16, 0, 0);
        }
    }
}

#define STEP_BEGIN { int nb_, nn_; phase_of(p + 1, nb_, nn_);                     \
                     if (nn_) stage_phase(blob, nb_, nn_, lds + (cur ^ 1) * 8192, wv, lane); \
                     const _Float16* Lb = lds + cur * 8192;
#define STEP_END     __syncthreads(); cur ^= 1; ++p; }
#define LDS_FRAG(fl) (((const half8*)Lb)[(fl) * 64 + lane])

__global__ __launch_bounds__(256, 1) void lstm_fused(
    const float* __restrict__ x, const float* __restrict__ b3,
    const float* __restrict__ hfc_b, const float* __restrict__ cfc_b,
    const float* __restrict__ mid_b, const float* __restrict__ o1b,
    const float* __restrict__ o2b, const float* __restrict__ o3b,
    const _Float16* __restrict__ blob, float* __restrict__ out)
{
    __shared__ _Float16 lds[16384];   // 2 x 16 KB

    int tid = threadIdx.x, lane = tid & 63, wv = tid >> 6;
    int g = lane >> 5;
    int batch = blockIdx.x * 128 + wv * 32 + (lane & 31);

    half8 xf[8], hA[8], cA[8], hB[8], cB[8], mfr[8];

    // x -> B-frag layout: chunk kc element j holds x[batch, kc*16 + kmap2(g,j)]
#pragma unroll
    for (int kc = 0; kc < 8; ++kc) {
        const float* xr = x + (size_t)batch * 128 + kc * 16 + 4 * g;
        float4 a = *(const float4*)xr;
        float4 b = *(const float4*)(xr + 8);
        half8 v;
        v[0]=(_Float16)a.x; v[1]=(_Float16)a.y; v[2]=(_Float16)a.z; v[3]=(_Float16)a.w;
        v[4]=(_Float16)b.x; v[5]=(_Float16)b.y; v[6]=(_Float16)b.z; v[7]=(_Float16)b.w;
        xf[kc] = v;
    }

    int p = 0, cur = 0;
    { int b0, n0; phase_of(0, b0, n0); stage_phase(blob, b0, n0, lds, wv, lane); }
    __syncthreads();

    // ---- generic pieces as lambdas (all register arrays statically indexed) ----
    auto head_mid = [&](const half8 (&hf)[8], const float* midbp) {
#pragma unroll
        for (int g2 = 0; g2 < 2; ++g2) {
            STEP_BEGIN
#pragma unroll
            for (int mtl = 0; mtl < 2; ++mtl) {
                const int mt = 2 * g2 + mtl;
                f32x16 acc = ZERO16;
#pragma unroll
                for (int kc = 0; kc < 8; ++kc) acc = MFMA32(LDS_FRAG(mtl * 8 + kc), hf[kc], acc);
#pragma unroll
                for (int t = 0; t < 4; ++t) {
                    float4 B4 = *(const float4*)(midbp + mt * 32 + 8 * t + 4 * g);
                    float bv[4] = {B4.x, B4.y, B4.z, B4.w};
#pragma unroll
                    for (int s = 0; s < 4; ++s) {
                        const int q = 4 * t + s;
                        float mv = fmaxf(acc[q] + bv[s], 0.0f);
                        if (q < 8) mfr[2 * mt][q] = (_Float16)mv; else mfr[2 * mt + 1][q - 8] = (_Float16)mv;
                    }
                }
            }
            STEP_END
        }
    };

    auto head_out2 = [&](int Nreal, float* obase, int rowlen, const float* outb) {
#pragma unroll
        for (int g2 = 0; g2 < 2; ++g2) {
            STEP_BEGIN
#pragma unroll
            for (int mtl = 0; mtl < 2; ++mtl) {
                const int mt = 2 * g2 + mtl;
                f32x16 acc = ZERO16;
#pragma unroll
                for (int kc = 0; kc < 8; ++kc) acc = MFMA32(LDS_FRAG(mtl * 8 + kc), mfr[kc], acc);
#pragma unroll
                for (int t = 0; t < 4; ++t)
#pragma unroll
                    for (int s = 0; s < 4; ++s) {
                        const int q = 4 * t + s;
                        int n = mt * 32 + 8 * t + 4 * g + s;
                        if (n < Nreal) obase[(size_t)batch * rowlen + n] = acc[q] + outb[n];
                    }
            }
            STEP_END
        }
    };

    auto fc_f = [&](const half8 (&bfr)[8], half8 (&io)[8], const float* fcb) {
#pragma unroll
        for (int g2 = 0; g2 < 2; ++g2) {
            STEP_BEGIN
#pragma unroll
            for (int mtl = 0; mtl < 2; ++mtl) {
                const int mt = 2 * g2 + mtl;
                f32x16 acc = ZERO16;
#pragma unroll
                for (int kc = 0; kc < 8; ++kc) acc = MFMA32(LDS_FRAG(mtl * 8 + kc), bfr[kc], acc);
#pragma unroll
                for (int t = 0; t < 4; ++t) {
                    float4 B4 = *(const float4*)(fcb + mt * 32 + 8 * t + 4 * g);
                    float bv[4] = {B4.x, B4.y, B4.z, B4.w};
#pragma unroll
                    for (int s = 0; s < 4; ++s) {
                        const int q = 4 * t + s;
                        float prev = (q < 8) ? (float)io[2 * mt][q] : (float)io[2 * mt + 1][q - 8];
                        float v = acc[q] + bv[s] + prev;
                        if (q < 8) io[2 * mt][q] = (_Float16)v; else io[2 * mt + 1][q - 8] = (_Float16)v;
                    }
                }
            }
            STEP_END
        }
    };

    auto zstage_f = [&](const half8 (&hf)[8], const half8 (&cp)[8],
                        half8 (&ho)[8], half8 (&co)[8], const float* bb, bool writeC) {
#pragma unroll
        for (int mt = 0; mt < 4; ++mt) {
            f32x16 ai = ZERO16, af = ZERO16, agg = ZERO16, ao = ZERO16;
            STEP_BEGIN   // X gates i,f
#pragma unroll
            for (int kc = 0; kc < 8; ++kc) { ai = MFMA32(LDS_FRAG(kc), xf[kc], ai);
                                             af = MFMA32(LDS_FRAG(8 + kc), xf[kc], af); }
            STEP_END
            STEP_BEGIN   // X gates g,o
#pragma unroll
            for (int kc = 0; kc < 8; ++kc) { agg = MFMA32(LDS_FRAG(kc), xf[kc], agg);
                                             ao  = MFMA32(LDS_FRAG(8 + kc), xf[kc], ao); }
            STEP_END
            STEP_BEGIN   // H gates i,f
#pragma unroll
            for (int kc = 0; kc < 8; ++kc) { ai = MFMA32(LDS_FRAG(kc), hf[kc], ai);
                                             af = MFMA32(LDS_FRAG(8 + kc), hf[kc], af); }
            STEP_END
            STEP_BEGIN   // H gates g,o + gate math
#pragma unroll
            for (int kc = 0; kc < 8; ++kc) { agg = MFMA32(LDS_FRAG(kc), hf[kc], agg);
                                             ao  = MFMA32(LDS_FRAG(8 + kc), hf[kc], ao); }
#pragma unroll
            for (int t = 0; t < 4; ++t) {
                float4 Bi = *(const float4*)(bb + 0   + mt * 32 + 8 * t + 4 * g);
                float4 Bf = *(const float4*)(bb + 128 + mt * 32 + 8 * t + 4 * g);
                float4 Bg = *(const float4*)(bb + 256 + mt * 32 + 8 * t + 4 * g);
                float4 Bo = *(const float4*)(bb + 384 + mt * 32 + 8 * t + 4 * g);
                float bi[4]={Bi.x,Bi.y,Bi.z,Bi.w}, bf[4]={Bf.x,Bf.y,Bf.z,Bf.w};
                float bg[4]={Bg.x,Bg.y,Bg.z,Bg.w}, bo[4]={Bo.x,Bo.y,Bo.z,Bo.w};
#pragma unroll
                for (int s = 0; s < 4; ++s) {
                    const int q = 4 * t + s;
                    float cprev = (q < 8) ? (float)cp[2 * mt][q] : (float)cp[2 * mt + 1][q - 8];
                    float si = sigz(ai[q] - L2E * bi[s]);
                    float sf = sigz(af[q] - L2E * bf[s]);
                    float tg = 1.0f - 2.0f * sigz(agg[q] + 2.0f * L2E * bg[s]);
                    float so = sigz(ao[q] - L2E * bo[s]);
                    float c  = sf * cprev + si * tg;
                    float h  = so * (1.0f - 2.0f * sigz(2.0f * L2E * c));
                    if (q < 8) ho[2 * mt][q] = (_Float16)h; else ho[2 * mt + 1][q - 8] = (_Float16)h;
                    if (writeC) { if (q < 8) co[2 * mt][q] = (_Float16)c; else co[2 * mt + 1][q - 8] = (_Float16)c; }
                }
            }
            STEP_END
        }
    };

    // ---- stage 1: h1,c1 (no f-gate, no Wh, cprev=0) — phases 0..7 ----
#pragma unroll
    for (int mt = 0; mt < 4; ++mt) {
        f32x16 ai = ZERO16, agg = ZERO16, ao = ZERO16;
        STEP_BEGIN   // gates i,(f staged but skipped)
#pragma unroll
        for (int kc = 0; kc < 8; ++kc) ai = MFMA32(LDS_FRAG(kc), xf[kc], ai);
        STEP_END
        STEP_BEGIN   // gates g,o + math
#pragma unroll
        for (int kc = 0; kc < 8; ++kc) { agg = MFMA32(LDS_FRAG(kc), xf[kc], agg);
                                         ao  = MFMA32(LDS_FRAG(8 + kc), xf[kc], ao); }
#pragma unroll
        for (int t = 0; t < 4; ++t) {
            float4 Bi = *(const float4*)(b3 + 0   + mt * 32 + 8 * t + 4 * g);
            float4 Bg = *(const float4*)(b3 + 256 + mt * 32 + 8 * t + 4 * g);
            float4 Bo = *(const float4*)(b3 + 384 + mt * 32 + 8 * t + 4 * g);
            float bi[4]={Bi.x,Bi.y,Bi.z,Bi.w}, bg[4]={Bg.x,Bg.y,Bg.z,Bg.w}, bo[4]={Bo.x,Bo.y,Bo.z,Bo.w};
#pragma unroll
            for (int s = 0; s < 4; ++s) {
                const int q = 4 * t + s;
                float si = sigz(ai[q] - L2E * bi[s]);
                float tg = 1.0f - 2.0f * sigz(agg[q] + 2.0f * L2E * bg[s]);
                float so = sigz(ao[q] - L2E * bo[s]);
                float c  = si * tg;
                float h  = so * (1.0f - 2.0f * sigz(2.0f * L2E * c));
                if (q < 8) { hA[2 * mt][q] = (_Float16)h; cA[2 * mt][q] = (_Float16)c; }
                else       { hA[2 * mt + 1][q - 8] = (_Float16)h; cA[2 * mt + 1][q - 8] = (_Float16)c; }
            }
        }
        STEP_END
    }

    head_mid(hA, mid_b);                                   // p 8,9
    head_out2(103, out, 103, o1b);                         // p 10,11
    zstage_f(hA, cA, hB, cB, b3 + 512, true);              // p 12..27  (h2,c2)
    fc_f(hB, hA, hfc_b);                                   // p 28,29   (h3_in -> hA)
    fc_f(cB, cA, cfc_b);                                   // p 30,31   (c3_in -> cA)
    head_mid(hB, mid_b + 128);                             // p 32,33
    head_out2(119, out + (size_t)65536 * 103, 119, o2b);   // p 34,35
    zstage_f(hA, cA, hB, cB, b3 + 1024, false);            // p 36..51  (h3 -> hB)
    head_mid(hB, mid_b + 256);                             // p 52,53

    STEP_BEGIN   // p 54: head3 out (1 Mtile, N=11)
    {
        f32x16 acc = ZERO16;
#pragma unroll
        for (int kc = 0; kc < 8; ++kc) acc = MFMA32(LDS_FRAG(kc), mfr[kc], acc);
        float* obase = out + (size_t)65536 * 222;
#pragma unroll
        for (int t = 0; t < 4; ++t)
#pragma unroll
            for (int s = 0; s < 4; ++s) {
                const int q = 4 * t + s;
                int n = 8 * t + 4 * g + s;
                if (n < 11) obase[(size_t)batch * 11 + n] = acc[q] + o3b[n];
            }
    }
    STEP_END
}

extern "C" void kernel_launch(void* const* d_in, const int* in_sizes, int n_in,
                              void* d_out, int out_size, void* d_ws, size_t ws_size,
                              hipStream_t stream)
{
    const float* x     = (const float*)d_in[0];
    const float* Wx    = (const float*)d_in[1];
    const float* Wh    = (const float*)d_in[2];
    const float* b3    = (const float*)d_in[3];
    const float* hfcW  = (const float*)d_in[4];
    const float* hfc_b = (const float*)d_in[5];
    const float* cfcW  = (const float*)d_in[6];
    const float* cfc_b = (const float*)d_in[7];
    const float* midW  = (const float*)d_in[8];
    const float* mid_b = (const float*)d_in[9];
    const float* o1W   = (const float*)d_in[10];
    const float* o1b   = (const float*)d_in[11];
    const float* o2W   = (const float*)d_in[12];
    const float* o2b   = (const float*)d_in[13];
    const float* o3W   = (const float*)d_in[14];
    const float* o3b   = (const float*)d_in[15];
    float* out = (float*)d_out;

    if (ws_size < (size_t)NBLOB_F16 * sizeof(_Float16)) return;  // ~872 KB scratch
    _Float16* blob = (_Float16*)d_ws;

    lstm_prep<<<NBLOB_F16 / 256, 256, 0, stream>>>(Wx, Wh, hfcW, cfcW, midW, o1W, o2W, o3W, blob);
    lstm_fused<<<512, 256, 0, stream>>>(x, b3, hfc_b, cfc_b, mid_b, o1b, o2b, o3b, blob, out);
}